// Round 2
// baseline (737.130 us; speedup 1.0000x reference)
//
#include <hip/hip_runtime.h>

#define H 2
#define C 64
#define IN_CH 64
#define HC (H*C)
#define NEG_SLOPE 0.2f

// ---------------- Kernel A: projection + attention dots ----------------
// grid = N blocks, block = 128 threads. Thread t computes xp[n, t] (t = h*64+c).
__global__ void proj_kernel(const float* __restrict__ x,
                            const float* __restrict__ W,
                            const float* __restrict__ att_src,
                            const float* __restrict__ att_dst,
                            float* __restrict__ xp,
                            float* __restrict__ asrc,
                            float* __restrict__ adst,
                            int N) {
    int n = blockIdx.x;
    int t = threadIdx.x;  // 0..127
    __shared__ float xs[IN_CH];
    if (t < IN_CH) xs[t] = x[(size_t)n * IN_CH + t];
    __syncthreads();

    // W row t: 64 floats = 16 float4
    const float4* wr = reinterpret_cast<const float4*>(W + (size_t)t * IN_CH);
    float acc = 0.f;
#pragma unroll
    for (int q = 0; q < 16; q++) {
        float4 w = wr[q];
        acc = fmaf(w.x, xs[q * 4 + 0], acc);
        acc = fmaf(w.y, xs[q * 4 + 1], acc);
        acc = fmaf(w.z, xs[q * 4 + 2], acc);
        acc = fmaf(w.w, xs[q * 4 + 3], acc);
    }
    xp[(size_t)n * HC + t] = acc;

    float as = acc * att_src[t];
    float ad = acc * att_dst[t];
#pragma unroll
    for (int d = 32; d > 0; d >>= 1) {
        as += __shfl_xor(as, d, 64);
        ad += __shfl_xor(ad, d, 64);
    }
    if ((t & 63) == 0) {
        int h = t >> 6;
        asrc[(size_t)n * H + h] = as;
        adst[(size_t)n * H + h] = ad;
    }
}

// ---------------- Kernel B: degree count (edges + self loops) ----------------
__global__ void degree_kernel(const int* __restrict__ dstE, int* __restrict__ deg,
                              int E, int N) {
    int i = blockIdx.x * blockDim.x + threadIdx.x;
    int total = E + N;
    if (i >= total) return;
    int d = (i < E) ? dstE[i] : (i - E);
    atomicAdd(&deg[d], 1);
}

// ---------------- Kernel C: single-block exclusive scan over deg ----------------
__global__ void scan_kernel(const int* __restrict__ deg, int* __restrict__ off,
                            int* __restrict__ cursor, int N) {
    const int T = 1024;
    int t = threadIdx.x;
    int chunk = (N + T - 1) / T;
    int beg = t * chunk;
    int end = min(beg + chunk, N);
    int sum = 0;
    for (int i = beg; i < end; i++) sum += deg[i];
    __shared__ int sh[T];
    sh[t] = sum;
    __syncthreads();
    for (int d = 1; d < T; d <<= 1) {
        int v = (t >= d) ? sh[t - d] : 0;
        __syncthreads();
        sh[t] += v;
        __syncthreads();
    }
    int run = sh[t] - sum;  // exclusive prefix at chunk start
    for (int i = beg; i < end; i++) {
        off[i] = run;
        cursor[i] = run;
        run += deg[i];
    }
    if (t == T - 1) off[N] = sh[T - 1];
}

// ---------------- Kernel D: scatter edges into CSR ----------------
__global__ void scatter_kernel(const int* __restrict__ srcE, const int* __restrict__ dstE,
                               int* __restrict__ cursor, int* __restrict__ csr,
                               int E, int N) {
    int i = blockIdx.x * blockDim.x + threadIdx.x;
    int total = E + N;
    if (i >= total) return;
    int s, d;
    if (i < E) { s = srcE[i]; d = dstE[i]; }
    else       { s = i - E;   d = s; }
    int pos = atomicAdd(&cursor[d], 1);
    csr[pos] = s;
}

// ---------------- Kernel E: per-dst softmax + weighted aggregation ----------------
// one wave (64 lanes) per destination node; block = 256 (4 waves)
__global__ void aggregate_kernel(const float* __restrict__ xp,
                                 const float* __restrict__ asrc,
                                 const float* __restrict__ adst,
                                 const int* __restrict__ off,
                                 const int* __restrict__ csr,
                                 const float* __restrict__ bias,
                                 const int* __restrict__ batch,
                                 float* __restrict__ out,
                                 float* __restrict__ gsum,
                                 int* __restrict__ gcnt,
                                 int N) {
    int n = blockIdx.x * 4 + (threadIdx.x >> 6);
    if (n >= N) return;
    int lane = threadIdx.x & 63;
    int o0 = off[n];
    int deg = off[n + 1] - o0;
    float ad0 = adst[(size_t)n * H + 0];
    float ad1 = adst[(size_t)n * H + 1];

    // pass 1: segment max (lanes parallel over edges)
    float m0 = -INFINITY, m1 = -INFINITY;
    for (int i = lane; i < deg; i += 64) {
        int s = csr[o0 + i];
        float e0 = asrc[(size_t)s * H + 0] + ad0;
        float e1 = asrc[(size_t)s * H + 1] + ad1;
        e0 = (e0 > 0.f) ? e0 : NEG_SLOPE * e0;
        e1 = (e1 > 0.f) ? e1 : NEG_SLOPE * e1;
        m0 = fmaxf(m0, e0);
        m1 = fmaxf(m1, e1);
    }
#pragma unroll
    for (int d = 32; d > 0; d >>= 1) {
        m0 = fmaxf(m0, __shfl_xor(m0, d, 64));
        m1 = fmaxf(m1, __shfl_xor(m1, d, 64));
    }

    // pass 2: sequential over edges; lanes hold channels (c=lane for h=0, h=1)
    float s0 = 0.f, s1 = 0.f, acc0 = 0.f, acc1 = 0.f;
    for (int j = 0; j < deg; j++) {
        int s = csr[o0 + j];
        float e0 = asrc[(size_t)s * H + 0] + ad0;
        float e1 = asrc[(size_t)s * H + 1] + ad1;
        e0 = (e0 > 0.f) ? e0 : NEG_SLOPE * e0;
        e1 = (e1 > 0.f) ? e1 : NEG_SLOPE * e1;
        float w0 = __expf(e0 - m0);
        float w1 = __expf(e1 - m1);
        s0 += w0;
        s1 += w1;
        const float* row = xp + (size_t)s * HC;
        acc0 = fmaf(w0, row[lane], acc0);
        acc1 = fmaf(w1, row[64 + lane], acc1);
    }
    float val = 0.5f * (acc0 / s0 + acc1 / s1) + bias[lane];
    out[(size_t)n * C + lane] = val;

    int g = batch[n];
    atomicAdd(&gsum[(size_t)g * C + lane], val);
    if (lane == 0) atomicAdd(&gcnt[g], 1);
}

// ---------------- Kernel F: pool finalize ----------------
__global__ void pool_kernel(const float* __restrict__ gsum, const int* __restrict__ gcnt,
                            float* __restrict__ out, int G, int baseOff) {
    int i = blockIdx.x * blockDim.x + threadIdx.x;
    if (i >= G * C) return;
    int g = i >> 6;
    float cnt = (float)max(gcnt[g], 1);
    out[baseOff + i] = gsum[i] / cnt;
}

extern "C" void kernel_launch(void* const* d_in, const int* in_sizes, int n_in,
                              void* d_out, int out_size, void* d_ws, size_t ws_size,
                              hipStream_t stream) {
    const float* x       = (const float*)d_in[0];
    const int*   edge    = (const int*)d_in[1];
    const int*   batch   = (const int*)d_in[2];
    const float* W       = (const float*)d_in[3];
    const float* att_src = (const float*)d_in[4];
    const float* att_dst = (const float*)d_in[5];
    const float* bias    = (const float*)d_in[6];

    int N = in_sizes[0] / IN_CH;
    int E = in_sizes[1] / 2;
    int G = out_size / C - N;
    int total = E + N;

    // workspace layout (all 256B-aligned)
    char* p = (char*)d_ws;
    auto alloc = [&](size_t bytes) {
        char* r = p;
        p += (bytes + 255) & ~(size_t)255;
        return r;
    };
    float* xp     = (float*)alloc((size_t)N * HC * 4);
    float* asrc   = (float*)alloc((size_t)N * H * 4);
    float* adst   = (float*)alloc((size_t)N * H * 4);
    int*   deg    = (int*)alloc((size_t)N * 4);
    int*   off    = (int*)alloc((size_t)(N + 1) * 4);
    int*   cursor = (int*)alloc((size_t)N * 4);
    int*   csr    = (int*)alloc((size_t)total * 4);
    float* gsum   = (float*)alloc((size_t)G * C * 4);
    int*   gcnt   = (int*)alloc((size_t)G * 4);

    hipMemsetAsync(deg, 0, (size_t)N * 4, stream);
    hipMemsetAsync(gsum, 0, (size_t)G * C * 4, stream);
    hipMemsetAsync(gcnt, 0, (size_t)G * 4, stream);

    const int* srcE = edge;
    const int* dstE = edge + E;

    proj_kernel<<<N, 128, 0, stream>>>(x, W, att_src, att_dst, xp, asrc, adst, N);
    degree_kernel<<<(total + 255) / 256, 256, 0, stream>>>(dstE, deg, E, N);
    scan_kernel<<<1, 1024, 0, stream>>>(deg, off, cursor, N);
    scatter_kernel<<<(total + 255) / 256, 256, 0, stream>>>(srcE, dstE, cursor, csr, E, N);
    aggregate_kernel<<<(N + 3) / 4, 256, 0, stream>>>(xp, asrc, adst, off, csr, bias, batch,
                                                      (float*)d_out, gsum, gcnt, N);
    pool_kernel<<<(G * C + 255) / 256, 256, 0, stream>>>(gsum, gcnt, (float*)d_out,
                                                         G, N * C);
}

// Round 3
// 425.302 us; speedup vs baseline: 1.7332x; 1.7332x over previous
//
#include <hip/hip_runtime.h>
#include <hip/hip_bf16.h>

#define H 2
#define C 64
#define IN_CH 64
#define HC (H*C)
#define NEG_SLOPE 0.2f

// ---------------- Kernel A: projection + attention dots ----------------
// W rows cached in VGPRs (64 regs/thread); grid-stride over nodes.
// xp stored bf16 [N,128]; asrc/adst fp32 float2 [N].
__global__ __launch_bounds__(128) void proj_kernel(
    const float* __restrict__ x, const float* __restrict__ W,
    const float* __restrict__ att_src, const float* __restrict__ att_dst,
    __hip_bfloat16* __restrict__ xp, float* __restrict__ asrc,
    float* __restrict__ adst, int N) {
    int t = threadIdx.x;  // output channel 0..127
    float w[64];
    const float4* wr = reinterpret_cast<const float4*>(W + (size_t)t * IN_CH);
#pragma unroll
    for (int q = 0; q < 16; q++) {
        float4 v = wr[q];
        w[4 * q] = v.x; w[4 * q + 1] = v.y; w[4 * q + 2] = v.z; w[4 * q + 3] = v.w;
    }
    float a_s = att_src[t], a_d = att_dst[t];
    int lane = t & 63, head = t >> 6;
    for (int n = blockIdx.x; n < N; n += gridDim.x) {
        const float* xr = x + (size_t)n * IN_CH;  // wave-uniform address -> s_load
        float acc = 0.f;
#pragma unroll
        for (int k = 0; k < 64; k++) acc = fmaf(w[k], xr[k], acc);
        xp[(size_t)n * HC + t] = __float2bfloat16(acc);
        float as = acc * a_s, ad = acc * a_d;
#pragma unroll
        for (int d = 32; d > 0; d >>= 1) {
            as += __shfl_xor(as, d, 64);
            ad += __shfl_xor(ad, d, 64);
        }
        if (lane == 0) {
            asrc[(size_t)n * H + head] = as;
            adst[(size_t)n * H + head] = ad;
        }
    }
}

// ---------------- Kernel B: degree count (real edges only; self-loop added in scan) ----
__global__ void degree_kernel(const int* __restrict__ dstE, int* __restrict__ deg, int E) {
    int i = (blockIdx.x * blockDim.x + threadIdx.x) * 4;
    if (i + 3 < E) {
        int4 d = *reinterpret_cast<const int4*>(dstE + i);
        atomicAdd(&deg[d.x], 1);
        atomicAdd(&deg[d.y], 1);
        atomicAdd(&deg[d.z], 1);
        atomicAdd(&deg[d.w], 1);
    } else {
        for (int j = i; j < E; j++) atomicAdd(&deg[dstE[j]], 1);
    }
}

// ---------------- Scan phase 1: per-1024-chunk sums of (deg+1) ----------------
__global__ __launch_bounds__(256) void scan1_kernel(const int* __restrict__ deg,
                                                    int* __restrict__ partial, int N) {
    int base = blockIdx.x * 1024;
    int end = min(base + 1024, N);
    int sum = 0;
    for (int i = base + threadIdx.x; i < end; i += 256) sum += deg[i] + 1;
#pragma unroll
    for (int d = 32; d > 0; d >>= 1) sum += __shfl_xor(sum, d, 64);
    __shared__ int sh[4];
    if ((threadIdx.x & 63) == 0) sh[threadIdx.x >> 6] = sum;
    __syncthreads();
    if (threadIdx.x == 0) partial[blockIdx.x] = sh[0] + sh[1] + sh[2] + sh[3];
}

// ---------------- Scan phase 2: exclusive scan of partials (nb <= 64) ----------------
__global__ void scan2_kernel(int* __restrict__ partial, int nb, int* __restrict__ offN) {
    int lane = threadIdx.x;
    int v = (lane < nb) ? partial[lane] : 0;
    int incl = v;
#pragma unroll
    for (int d = 1; d < 64; d <<= 1) {
        int t = __shfl_up(incl, d, 64);
        if (lane >= d) incl += t;
    }
    if (lane < nb) partial[lane] = incl - v;  // exclusive base per chunk
    if (lane == 63) offN[0] = incl;           // total = E + N
}

// ---------------- Scan phase 3: write off/cursor, place self-loops ----------------
__global__ __launch_bounds__(256) void scan3_kernel(const int* __restrict__ deg,
                                                    const int* __restrict__ partial,
                                                    int* __restrict__ off, int* __restrict__ cursor,
                                                    int* __restrict__ csr, int N) {
    int b = blockIdx.x, t = threadIdx.x;
    int i0 = b * 1024 + t * 4;
    int e[4];
    int s = 0;
#pragma unroll
    for (int j = 0; j < 4; j++) {
        int i = i0 + j;
        e[j] = (i < N) ? deg[i] + 1 : 0;
        s += e[j];
    }
    __shared__ int sh[256];
    sh[t] = s;
    __syncthreads();
    for (int d = 1; d < 256; d <<= 1) {
        int v = (t >= d) ? sh[t - d] : 0;
        __syncthreads();
        sh[t] += v;
        __syncthreads();
    }
    int run = partial[b] + sh[t] - s;
#pragma unroll
    for (int j = 0; j < 4; j++) {
        int i = i0 + j;
        if (i < N) {
            off[i] = run;
            csr[run] = i;          // self-loop in slot 0
            cursor[i] = run + 1;   // edges start after self-loop
            run += e[j];
        }
    }
}

// ---------------- Kernel D: scatter edges into CSR ----------------
__global__ void scatter_kernel(const int* __restrict__ srcE, const int* __restrict__ dstE,
                               int* __restrict__ cursor, int* __restrict__ csr, int E) {
    int i = (blockIdx.x * blockDim.x + threadIdx.x) * 4;
    if (i + 3 < E) {
        int4 sv = *reinterpret_cast<const int4*>(srcE + i);
        int4 dv = *reinterpret_cast<const int4*>(dstE + i);
        int p;
        p = atomicAdd(&cursor[dv.x], 1); csr[p] = sv.x;
        p = atomicAdd(&cursor[dv.y], 1); csr[p] = sv.y;
        p = atomicAdd(&cursor[dv.z], 1); csr[p] = sv.z;
        p = atomicAdd(&cursor[dv.w], 1); csr[p] = sv.w;
    } else {
        for (int j = i; j < E; j++) {
            int p = atomicAdd(&cursor[dstE[j]], 1);
            csr[p] = srcE[j];
        }
    }
}

// ---------------- Kernel E: softmax + aggregation, one wave per dst node ----------------
// Lane-parallel weight compute; channel loop: shfl-broadcast + coalesced 256B bf16 gather.
// Lane L holds flat channels {2L, 2L+1}: L<32 -> head0, L>=32 -> head1.
__global__ __launch_bounds__(256) void aggregate_kernel(
    const __hip_bfloat16* __restrict__ xp, const float2* __restrict__ asrc,
    const float2* __restrict__ adst, const int* __restrict__ off,
    const int* __restrict__ csr, const float* __restrict__ bias,
    const int* __restrict__ batch, float* __restrict__ out,
    float* __restrict__ gsum, int* __restrict__ gcnt, int N) {
    int n = blockIdx.x * 4 + (threadIdx.x >> 6);
    if (n >= N) return;
    int lane = threadIdx.x & 63;
    int o0 = off[n];
    int deg = off[n + 1] - o0;
    float2 ad = adst[n];

    // chunk 0: lane j owns edge j
    int idx0 = 0;
    float e0 = -INFINITY, e1 = -INFINITY;
    if (lane < deg) {
        idx0 = csr[o0 + lane];
        float2 as = asrc[idx0];
        e0 = as.x + ad.x; e0 = (e0 > 0.f) ? e0 : NEG_SLOPE * e0;
        e1 = as.y + ad.y; e1 = (e1 > 0.f) ? e1 : NEG_SLOPE * e1;
    }
    float m0 = e0, m1 = e1;
    for (int i = 64 + lane; i < deg; i += 64) {
        int s2 = csr[o0 + i];
        float2 as = asrc[s2];
        float t0 = as.x + ad.x; t0 = (t0 > 0.f) ? t0 : NEG_SLOPE * t0;
        float t1 = as.y + ad.y; t1 = (t1 > 0.f) ? t1 : NEG_SLOPE * t1;
        m0 = fmaxf(m0, t0);
        m1 = fmaxf(m1, t1);
    }
#pragma unroll
    for (int d = 32; d > 0; d >>= 1) {
        m0 = fmaxf(m0, __shfl_xor(m0, d, 64));
        m1 = fmaxf(m1, __shfl_xor(m1, d, 64));
    }

    float w0 = (lane < deg) ? __expf(e0 - m0) : 0.f;
    float w1 = (lane < deg) ? __expf(e1 - m1) : 0.f;
    float s0 = w0, s1 = w1;

    const uint* xpw = reinterpret_cast<const uint*>(xp);
    float accx = 0.f, accy = 0.f;
    int cnt = min(deg, 64);
#pragma unroll 4
    for (int j = 0; j < cnt; j++) {
        int s2 = __shfl(idx0, j, 64);
        float a0 = __shfl(w0, j, 64);
        float a1 = __shfl(w1, j, 64);
        float wgt = (lane < 32) ? a0 : a1;
        uint u = xpw[(size_t)s2 * 64 + lane];
        accx = fmaf(wgt, __uint_as_float(u << 16), accx);
        accy = fmaf(wgt, __uint_as_float(u & 0xffff0000u), accy);
    }
    for (int base = 64; base < deg; base += 64) {
        int i = base + lane;
        int idx = 0;
        float v0 = 0.f, v1 = 0.f;
        if (i < deg) {
            idx = csr[o0 + i];
            float2 as = asrc[idx];
            float t0 = as.x + ad.x; t0 = (t0 > 0.f) ? t0 : NEG_SLOPE * t0;
            float t1 = as.y + ad.y; t1 = (t1 > 0.f) ? t1 : NEG_SLOPE * t1;
            v0 = __expf(t0 - m0);
            v1 = __expf(t1 - m1);
        }
        s0 += v0;
        s1 += v1;
        int c2 = min(deg - base, 64);
#pragma unroll 4
        for (int j = 0; j < c2; j++) {
            int s2 = __shfl(idx, j, 64);
            float a0 = __shfl(v0, j, 64);
            float a1 = __shfl(v1, j, 64);
            float wgt = (lane < 32) ? a0 : a1;
            uint u = xpw[(size_t)s2 * 64 + lane];
            accx = fmaf(wgt, __uint_as_float(u << 16), accx);
            accy = fmaf(wgt, __uint_as_float(u & 0xffff0000u), accy);
        }
    }
#pragma unroll
    for (int d = 32; d > 0; d >>= 1) {
        s0 += __shfl_xor(s0, d, 64);
        s1 += __shfl_xor(s1, d, 64);
    }
    float inv = (lane < 32) ? (1.f / s0) : (1.f / s1);
    accx *= inv;
    accy *= inv;
    // head mean: lane L (h0 ch 2L,2L+1) pairs with lane L+32 (h1 ch 2L,2L+1)
    float ox = 0.5f * (accx + __shfl_xor(accx, 32, 64));
    float oy = 0.5f * (accy + __shfl_xor(accy, 32, 64));
    int g = batch[n];
    if (lane < 32) {
        float vx = ox + bias[2 * lane];
        float vy = oy + bias[2 * lane + 1];
        *reinterpret_cast<float2*>(out + (size_t)n * C + 2 * lane) = make_float2(vx, vy);
        atomicAdd(&gsum[(size_t)g * C + 2 * lane], vx);
        atomicAdd(&gsum[(size_t)g * C + 2 * lane + 1], vy);
    }
    if (lane == 0) atomicAdd(&gcnt[g], 1);
}

// ---------------- Kernel F: pool finalize ----------------
__global__ void pool_kernel(const float* __restrict__ gsum, const int* __restrict__ gcnt,
                            float* __restrict__ out, int G, int baseOff) {
    int i = blockIdx.x * blockDim.x + threadIdx.x;
    if (i >= G * C) return;
    int g = i >> 6;
    float cnt = (float)max(gcnt[g], 1);
    out[baseOff + i] = gsum[i] / cnt;
}

extern "C" void kernel_launch(void* const* d_in, const int* in_sizes, int n_in,
                              void* d_out, int out_size, void* d_ws, size_t ws_size,
                              hipStream_t stream) {
    const float* x       = (const float*)d_in[0];
    const int*   edge    = (const int*)d_in[1];
    const int*   batch   = (const int*)d_in[2];
    const float* W       = (const float*)d_in[3];
    const float* att_src = (const float*)d_in[4];
    const float* att_dst = (const float*)d_in[5];
    const float* bias    = (const float*)d_in[6];

    int N = in_sizes[0] / IN_CH;
    int E = in_sizes[1] / 2;
    int G = out_size / C - N;
    int total = E + N;
    int nb = (N + 1023) / 1024;  // must be <= 64 (N <= 65536)

    char* p = (char*)d_ws;
    auto alloc = [&](size_t bytes) {
        char* r = p;
        p += (bytes + 255) & ~(size_t)255;
        return r;
    };
    __hip_bfloat16* xp = (__hip_bfloat16*)alloc((size_t)N * HC * 2);
    float* asrc   = (float*)alloc((size_t)N * H * 4);
    float* adst   = (float*)alloc((size_t)N * H * 4);
    int*   deg    = (int*)alloc((size_t)N * 4);
    int*   off    = (int*)alloc((size_t)(N + 1) * 4);
    int*   cursor = (int*)alloc((size_t)N * 4);
    int*   csr    = (int*)alloc((size_t)total * 4);
    int*   partial= (int*)alloc((size_t)(nb + 1) * 4);
    float* gsum   = (float*)alloc((size_t)G * C * 4);
    int*   gcnt   = (int*)alloc((size_t)G * 4);

    hipMemsetAsync(deg, 0, (size_t)N * 4, stream);
    hipMemsetAsync(gsum, 0, (size_t)G * C * 4, stream);
    hipMemsetAsync(gcnt, 0, (size_t)G * 4, stream);

    const int* srcE = edge;
    const int* dstE = edge + E;

    proj_kernel<<<2048, 128, 0, stream>>>(x, W, att_src, att_dst, xp, asrc, adst, N);
    degree_kernel<<<(E / 4 + 256) / 256, 256, 0, stream>>>(dstE, deg, E);
    scan1_kernel<<<nb, 256, 0, stream>>>(deg, partial, N);
    scan2_kernel<<<1, 64, 0, stream>>>(partial, nb, off + N);
    scan3_kernel<<<nb, 256, 0, stream>>>(deg, partial, off, cursor, csr, N);
    scatter_kernel<<<(E / 4 + 256) / 256, 256, 0, stream>>>(srcE, dstE, cursor, csr, E);
    aggregate_kernel<<<(N + 3) / 4, 256, 0, stream>>>(xp, (const float2*)asrc, (const float2*)adst,
                                                      off, csr, bias, batch,
                                                      (float*)d_out, gsum, gcnt, N);
    pool_kernel<<<(G * C + 255) / 256, 256, 0, stream>>>(gsum, gcnt, (float*)d_out, G, N * C);
}

// Round 4
// 353.540 us; speedup vs baseline: 2.0850x; 1.2030x over previous
//
#include <hip/hip_runtime.h>
#include <hip/hip_bf16.h>

#define H 2
#define C 64
#define IN_CH 64
#define HC (H*C)
#define NEG_SLOPE 0.2f
#define NBUCK_MAX 256
#define NBLK 256   // blocks for hist/scatter passes

// ---------------- Kernel A: projection + attention dots ----------------
// W rows cached in VGPRs (64 regs/thread); grid-stride over nodes.
// xp stored bf16 [N,128]; asrc/adst fp32 float2 [N].
__global__ __launch_bounds__(128) void proj_kernel(
    const float* __restrict__ x, const float* __restrict__ W,
    const float* __restrict__ att_src, const float* __restrict__ att_dst,
    __hip_bfloat16* __restrict__ xp, float* __restrict__ asrc,
    float* __restrict__ adst, int N) {
    int t = threadIdx.x;  // output channel 0..127
    float w[64];
    const float4* wr = reinterpret_cast<const float4*>(W + (size_t)t * IN_CH);
#pragma unroll
    for (int q = 0; q < 16; q++) {
        float4 v = wr[q];
        w[4 * q] = v.x; w[4 * q + 1] = v.y; w[4 * q + 2] = v.z; w[4 * q + 3] = v.w;
    }
    float a_s = att_src[t], a_d = att_dst[t];
    int lane = t & 63, head = t >> 6;
    for (int n = blockIdx.x; n < N; n += gridDim.x) {
        const float* xr = x + (size_t)n * IN_CH;  // wave-uniform address -> s_load
        float acc = 0.f;
#pragma unroll
        for (int k = 0; k < 64; k++) acc = fmaf(w[k], xr[k], acc);
        xp[(size_t)n * HC + t] = __float2bfloat16(acc);
        float as = acc * a_s, ad = acc * a_d;
#pragma unroll
        for (int d = 32; d > 0; d >>= 1) {
            as += __shfl_xor(as, d, 64);
            ad += __shfl_xor(ad, d, 64);
        }
        if (lane == 0) {
            asrc[(size_t)n * H + head] = as;
            adst[(size_t)n * H + head] = ad;
        }
    }
}

// ---------------- Bucket sort pass 1: per-block bucket histogram ----------------
__global__ __launch_bounds__(256) void hist_kernel(const int* __restrict__ dstE,
                                                   int* __restrict__ hist,
                                                   int E, int nbuck, int chunkE) {
    __shared__ int lh[NBUCK_MAX];
    for (int t = threadIdx.x; t < nbuck; t += 256) lh[t] = 0;
    __syncthreads();
    int beg = blockIdx.x * chunkE;
    int end = min(beg + chunkE, E);
    for (int i = beg + threadIdx.x; i < end; i += 256)
        atomicAdd(&lh[dstE[i] >> 8], 1);
    __syncthreads();
    for (int t = threadIdx.x; t < nbuck; t += 256)
        hist[t * NBLK + blockIdx.x] = lh[t];  // bucket-major for scan
}

// ---------------- Bucket sort pass 2: scan of (bucket,block) counts ----------------
__global__ __launch_bounds__(1024) void scan_hist_kernel(int* __restrict__ hist,
                                                         int* __restrict__ bucketBase,
                                                         int nbuck) {
    int total = nbuck * NBLK;
    int t = threadIdx.x;
    int chunk = (total + 1023) / 1024;
    int beg = t * chunk, end = min(beg + chunk, total);
    int sum = 0;
    for (int i = beg; i < end; i++) sum += hist[i];
    __shared__ int sh[1024];
    sh[t] = sum;
    __syncthreads();
    for (int d = 1; d < 1024; d <<= 1) {
        int v = (t >= d) ? sh[t - d] : 0;
        __syncthreads();
        sh[t] += v;
        __syncthreads();
    }
    int run = sh[t] - sum;  // exclusive prefix at chunk start
    for (int i = beg; i < end; i++) {
        int v = hist[i];
        hist[i] = run;
        if ((i & (NBLK - 1)) == 0) bucketBase[i / NBLK] = run;
        run += v;
    }
    if (t == 1023) bucketBase[nbuck] = sh[1023];  // == E
}

// ---------------- Bucket sort pass 3: scatter into bucket-ordered staging ----------------
// per-(block,bucket) write streams are sequential -> no write amplification
__global__ __launch_bounds__(256) void bucket_scatter_kernel(
    const int* __restrict__ srcE, const int* __restrict__ dstE,
    const int* __restrict__ hist, int2* __restrict__ staged,
    int E, int nbuck, int chunkE) {
    __shared__ int cur[NBUCK_MAX];
    for (int t = threadIdx.x; t < nbuck; t += 256)
        cur[t] = hist[t * NBLK + blockIdx.x];
    __syncthreads();
    int beg = blockIdx.x * chunkE;
    int end = min(beg + chunkE, E);
    for (int i = beg + threadIdx.x; i < end; i += 256) {
        int s = srcE[i], d = dstE[i];
        int pos = atomicAdd(&cur[d >> 8], 1);
        staged[pos] = make_int2(s, d);
    }
}

// ---------------- Bucket sort pass 4: per-bucket CSR finalize ----------------
// one block per bucket; all writes land in an L2-resident ~33KB window
__global__ __launch_bounds__(256) void bucket_csr_kernel(
    const int2* __restrict__ staged, const int* __restrict__ bucketBase,
    int* __restrict__ off, int* __restrict__ csr, int N) {
    int b = blockIdx.x, t = threadIdx.x;
    int beg = bucketBase[b], end = bucketBase[b + 1];
    __shared__ int lh[256], sh[256], cur[256];
    lh[t] = 0;
    __syncthreads();
    for (int i = beg + t; i < end; i += 256)
        atomicAdd(&lh[staged[i].y & 255], 1);
    __syncthreads();
    int v = lh[t];
    sh[t] = v;
    __syncthreads();
    for (int d = 1; d < 256; d <<= 1) {
        int u = (t >= d) ? sh[t - d] : 0;
        __syncthreads();
        sh[t] += u;
        __syncthreads();
    }
    int ex = sh[t] - v;  // bucket-local exclusive prefix
    int nd = b * 256 + t;
    if (nd < N) off[nd] = beg + ex;
    if (nd == N - 1) off[N] = end;  // last bucket: end == E
    cur[t] = beg + ex;
    __syncthreads();
    for (int i = beg + t; i < end; i += 256) {
        int2 e = staged[i];
        int pos = atomicAdd(&cur[e.y & 255], 1);
        csr[pos] = e.x;
    }
}

// ---------------- Kernel E: softmax + aggregation, one wave per dst node ----------------
// Self-loop handled analytically (not in csr). Lane L holds flat channels {2L,2L+1}:
// L<32 -> head0, L>=32 -> head1.
__global__ __launch_bounds__(256) void aggregate_kernel(
    const __hip_bfloat16* __restrict__ xp, const float2* __restrict__ asrc,
    const float2* __restrict__ adst, const int* __restrict__ off,
    const int* __restrict__ csr, const float* __restrict__ bias,
    const int* __restrict__ batch, float* __restrict__ out,
    float* __restrict__ gsum, int* __restrict__ gcnt, int N) {
    int n = blockIdx.x * 4 + (threadIdx.x >> 6);
    if (n >= N) return;
    int lane = threadIdx.x & 63;
    int o0 = off[n];
    int degE = off[n + 1] - o0;  // real edges only
    float2 ad = adst[n];
    float2 asn = asrc[n];
    float es0 = asn.x + ad.x; es0 = (es0 > 0.f) ? es0 : NEG_SLOPE * es0;
    float es1 = asn.y + ad.y; es1 = (es1 > 0.f) ? es1 : NEG_SLOPE * es1;

    // chunk 0: lane j owns edge j
    int idx0 = 0;
    float e0 = -INFINITY, e1 = -INFINITY;
    if (lane < degE) {
        idx0 = csr[o0 + lane];
        float2 as = asrc[idx0];
        e0 = as.x + ad.x; e0 = (e0 > 0.f) ? e0 : NEG_SLOPE * e0;
        e1 = as.y + ad.y; e1 = (e1 > 0.f) ? e1 : NEG_SLOPE * e1;
    }
    float m0 = fmaxf(es0, e0), m1 = fmaxf(es1, e1);
    for (int i = 64 + lane; i < degE; i += 64) {
        int s2 = csr[o0 + i];
        float2 as = asrc[s2];
        float t0 = as.x + ad.x; t0 = (t0 > 0.f) ? t0 : NEG_SLOPE * t0;
        float t1 = as.y + ad.y; t1 = (t1 > 0.f) ? t1 : NEG_SLOPE * t1;
        m0 = fmaxf(m0, t0);
        m1 = fmaxf(m1, t1);
    }
#pragma unroll
    for (int d = 32; d > 0; d >>= 1) {
        m0 = fmaxf(m0, __shfl_xor(m0, d, 64));
        m1 = fmaxf(m1, __shfl_xor(m1, d, 64));
    }

    float w0 = (lane < degE) ? __expf(e0 - m0) : 0.f;
    float w1 = (lane < degE) ? __expf(e1 - m1) : 0.f;
    float s0 = w0, s1 = w1;

    const uint* xpw = reinterpret_cast<const uint*>(xp);
    float accx = 0.f, accy = 0.f;
    int cnt = min(degE, 64);
#pragma unroll 4
    for (int j = 0; j < cnt; j++) {
        int s2 = __shfl(idx0, j, 64);
        float a0 = __shfl(w0, j, 64);
        float a1 = __shfl(w1, j, 64);
        float wgt = (lane < 32) ? a0 : a1;
        uint u = xpw[(size_t)s2 * 64 + lane];
        accx = fmaf(wgt, __uint_as_float(u << 16), accx);
        accy = fmaf(wgt, __uint_as_float(u & 0xffff0000u), accy);
    }
    for (int base = 64; base < degE; base += 64) {
        int i = base + lane;
        int idx = 0;
        float v0 = 0.f, v1 = 0.f;
        if (i < degE) {
            idx = csr[o0 + i];
            float2 as = asrc[idx];
            float t0 = as.x + ad.x; t0 = (t0 > 0.f) ? t0 : NEG_SLOPE * t0;
            float t1 = as.y + ad.y; t1 = (t1 > 0.f) ? t1 : NEG_SLOPE * t1;
            v0 = __expf(t0 - m0);
            v1 = __expf(t1 - m1);
        }
        s0 += v0;
        s1 += v1;
        int c2 = min(degE - base, 64);
#pragma unroll 4
        for (int j = 0; j < c2; j++) {
            int s2 = __shfl(idx, j, 64);
            float a0 = __shfl(v0, j, 64);
            float a1 = __shfl(v1, j, 64);
            float wgt = (lane < 32) ? a0 : a1;
            uint u = xpw[(size_t)s2 * 64 + lane];
            accx = fmaf(wgt, __uint_as_float(u << 16), accx);
            accy = fmaf(wgt, __uint_as_float(u & 0xffff0000u), accy);
        }
    }
#pragma unroll
    for (int d = 32; d > 0; d >>= 1) {
        s0 += __shfl_xor(s0, d, 64);
        s1 += __shfl_xor(s1, d, 64);
    }
    // self-loop contribution (wave-uniform weights)
    float ws0 = __expf(es0 - m0), ws1 = __expf(es1 - m1);
    s0 += ws0;
    s1 += ws1;
    {
        float wgt = (lane < 32) ? ws0 : ws1;
        uint u = xpw[(size_t)n * 64 + lane];
        accx = fmaf(wgt, __uint_as_float(u << 16), accx);
        accy = fmaf(wgt, __uint_as_float(u & 0xffff0000u), accy);
    }
    float inv = (lane < 32) ? (1.f / s0) : (1.f / s1);
    accx *= inv;
    accy *= inv;
    // head mean: lane L (h0 ch 2L,2L+1) pairs with lane L+32 (h1 ch 2L,2L+1)
    float ox = 0.5f * (accx + __shfl_xor(accx, 32, 64));
    float oy = 0.5f * (accy + __shfl_xor(accy, 32, 64));
    int g = batch[n];
    if (lane < 32) {
        float vx = ox + bias[2 * lane];
        float vy = oy + bias[2 * lane + 1];
        *reinterpret_cast<float2*>(out + (size_t)n * C + 2 * lane) = make_float2(vx, vy);
        atomicAdd(&gsum[(size_t)g * C + 2 * lane], vx);
        atomicAdd(&gsum[(size_t)g * C + 2 * lane + 1], vy);
    }
    if (lane == 0) atomicAdd(&gcnt[g], 1);
}

// ---------------- Kernel F: pool finalize ----------------
__global__ void pool_kernel(const float* __restrict__ gsum, const int* __restrict__ gcnt,
                            float* __restrict__ out, int G, int baseOff) {
    int i = blockIdx.x * blockDim.x + threadIdx.x;
    if (i >= G * C) return;
    int g = i >> 6;
    float cnt = (float)max(gcnt[g], 1);
    out[baseOff + i] = gsum[i] / cnt;
}

extern "C" void kernel_launch(void* const* d_in, const int* in_sizes, int n_in,
                              void* d_out, int out_size, void* d_ws, size_t ws_size,
                              hipStream_t stream) {
    const float* x       = (const float*)d_in[0];
    const int*   edge    = (const int*)d_in[1];
    const int*   batch   = (const int*)d_in[2];
    const float* W       = (const float*)d_in[3];
    const float* att_src = (const float*)d_in[4];
    const float* att_dst = (const float*)d_in[5];
    const float* bias    = (const float*)d_in[6];

    int N = in_sizes[0] / IN_CH;
    int E = in_sizes[1] / 2;
    int G = out_size / C - N;
    int nbuck = (N + 255) >> 8;            // 196 for N=50000 (must be <= 256)
    int chunkE = (E + NBLK - 1) / NBLK;

    char* p = (char*)d_ws;
    auto alloc = [&](size_t bytes) {
        char* r = p;
        p += (bytes + 255) & ~(size_t)255;
        return r;
    };
    __hip_bfloat16* xp = (__hip_bfloat16*)alloc((size_t)N * HC * 2);
    float* asrc    = (float*)alloc((size_t)N * H * 4);
    float* adst    = (float*)alloc((size_t)N * H * 4);
    int*   hist    = (int*)alloc((size_t)nbuck * NBLK * 4);
    int*   bucketBase = (int*)alloc((size_t)(nbuck + 1) * 4);
    int*   off     = (int*)alloc((size_t)(N + 1) * 4);
    int2*  staged  = (int2*)alloc((size_t)E * 8);
    int*   csr     = (int*)alloc((size_t)E * 4);
    float* gsum    = (float*)alloc((size_t)G * C * 4);
    int*   gcnt    = (int*)alloc((size_t)G * 4);

    hipMemsetAsync(gsum, 0, (size_t)G * C * 4, stream);
    hipMemsetAsync(gcnt, 0, (size_t)G * 4, stream);

    const int* srcE = edge;
    const int* dstE = edge + E;

    proj_kernel<<<2048, 128, 0, stream>>>(x, W, att_src, att_dst, xp, asrc, adst, N);
    hist_kernel<<<NBLK, 256, 0, stream>>>(dstE, hist, E, nbuck, chunkE);
    scan_hist_kernel<<<1, 1024, 0, stream>>>(hist, bucketBase, nbuck);
    bucket_scatter_kernel<<<NBLK, 256, 0, stream>>>(srcE, dstE, hist, staged, E, nbuck, chunkE);
    bucket_csr_kernel<<<nbuck, 256, 0, stream>>>(staged, bucketBase, off, csr, N);
    aggregate_kernel<<<(N + 3) / 4, 256, 0, stream>>>(xp, (const float2*)asrc, (const float2*)adst,
                                                      off, csr, bias, batch,
                                                      (float*)d_out, gsum, gcnt, N);
    pool_kernel<<<(G * C + 255) / 256, 256, 0, stream>>>(gsum, gcnt, (float*)d_out, G, N * C);
}

// Round 6
// 311.611 us; speedup vs baseline: 2.3655x; 1.1346x over previous
//
#include <hip/hip_runtime.h>
#include <hip/hip_bf16.h>

#define H 2
#define C 64
#define IN_CH 64
#define HC (H*C)
#define NEG_SLOPE 0.2f
#define NBUCK_MAX 256
#define NBLK 256   // blocks for hist/scatter passes

// ---------------- Kernel A: projection + attention dots ----------------
__global__ __launch_bounds__(128) void proj_kernel(
    const float* __restrict__ x, const float* __restrict__ W,
    const float* __restrict__ att_src, const float* __restrict__ att_dst,
    __hip_bfloat16* __restrict__ xp, float* __restrict__ asrc,
    float* __restrict__ adst, int N) {
    int t = threadIdx.x;  // output channel 0..127
    float w[64];
    const float4* wr = reinterpret_cast<const float4*>(W + (size_t)t * IN_CH);
#pragma unroll
    for (int q = 0; q < 16; q++) {
        float4 v = wr[q];
        w[4 * q] = v.x; w[4 * q + 1] = v.y; w[4 * q + 2] = v.z; w[4 * q + 3] = v.w;
    }
    float a_s = att_src[t], a_d = att_dst[t];
    int lane = t & 63, head = t >> 6;
    for (int n = blockIdx.x; n < N; n += gridDim.x) {
        const float* xr = x + (size_t)n * IN_CH;  // wave-uniform address
        float acc = 0.f;
#pragma unroll
        for (int k = 0; k < 64; k++) acc = fmaf(w[k], xr[k], acc);
        xp[(size_t)n * HC + t] = __float2bfloat16(acc);
        float as = acc * a_s, ad = acc * a_d;
#pragma unroll
        for (int d = 32; d > 0; d >>= 1) {
            as += __shfl_xor(as, d, 64);
            ad += __shfl_xor(ad, d, 64);
        }
        if (lane == 0) {
            asrc[(size_t)n * H + head] = as;
            adst[(size_t)n * H + head] = ad;
        }
    }
}

// ---------------- Bucket sort pass 1: per-block bucket histogram ----------------
__global__ __launch_bounds__(256) void hist_kernel(const int* __restrict__ dstE,
                                                   int* __restrict__ hist,
                                                   int E, int nbuck, int chunkE) {
    __shared__ int lh[NBUCK_MAX];
    for (int t = threadIdx.x; t < nbuck; t += 256) lh[t] = 0;
    __syncthreads();
    int beg = blockIdx.x * chunkE;
    int end = min(beg + chunkE, E);
    for (int i = beg + threadIdx.x; i < end; i += 256)
        atomicAdd(&lh[dstE[i] >> 8], 1);
    __syncthreads();
    for (int t = threadIdx.x; t < nbuck; t += 256)
        hist[t * NBLK + blockIdx.x] = lh[t];  // bucket-major for scan
}

// ---------------- Bucket sort pass 2: scan of (bucket,block) counts ----------------
__global__ __launch_bounds__(1024) void scan_hist_kernel(int* __restrict__ hist,
                                                         int* __restrict__ bucketBase,
                                                         int nbuck) {
    int total = nbuck * NBLK;
    int t = threadIdx.x;
    int chunk = (total + 1023) / 1024;
    int beg = t * chunk, end = min(beg + chunk, total);
    int sum = 0;
    for (int i = beg; i < end; i++) sum += hist[i];
    __shared__ int sh[1024];
    sh[t] = sum;
    __syncthreads();
    for (int d = 1; d < 1024; d <<= 1) {
        int v = (t >= d) ? sh[t - d] : 0;
        __syncthreads();
        sh[t] += v;
        __syncthreads();
    }
    int run = sh[t] - sum;
    for (int i = beg; i < end; i++) {
        int v = hist[i];
        hist[i] = run;
        if ((i & (NBLK - 1)) == 0) bucketBase[i / NBLK] = run;
        run += v;
    }
    if (t == 1023) bucketBase[nbuck] = sh[1023];  // == E
}

// ---------------- Bucket sort pass 3: scatter into bucket-ordered staging ----------------
__global__ __launch_bounds__(256) void bucket_scatter_kernel(
    const int* __restrict__ srcE, const int* __restrict__ dstE,
    const int* __restrict__ hist, int2* __restrict__ staged,
    int E, int nbuck, int chunkE) {
    __shared__ int cur[NBUCK_MAX];
    for (int t = threadIdx.x; t < nbuck; t += 256)
        cur[t] = hist[t * NBLK + blockIdx.x];
    __syncthreads();
    int beg = blockIdx.x * chunkE;
    int end = min(beg + chunkE, E);
    for (int i = beg + threadIdx.x; i < end; i += 256) {
        int s = srcE[i], d = dstE[i];
        int pos = atomicAdd(&cur[d >> 8], 1);
        staged[pos] = make_int2(s, d);
    }
}

// ---------------- Bucket sort pass 4: per-bucket CSR finalize ----------------
__global__ __launch_bounds__(256) void bucket_csr_kernel(
    const int2* __restrict__ staged, const int* __restrict__ bucketBase,
    int* __restrict__ off, int* __restrict__ csr, int N) {
    int b = blockIdx.x, t = threadIdx.x;
    int beg = bucketBase[b], end = bucketBase[b + 1];
    __shared__ int lh[256], sh[256], cur[256];
    lh[t] = 0;
    __syncthreads();
    for (int i = beg + t; i < end; i += 256)
        atomicAdd(&lh[staged[i].y & 255], 1);
    __syncthreads();
    int v = lh[t];
    sh[t] = v;
    __syncthreads();
    for (int d = 1; d < 256; d <<= 1) {
        int u = (t >= d) ? sh[t - d] : 0;
        __syncthreads();
        sh[t] += u;
        __syncthreads();
    }
    int ex = sh[t] - v;
    int nd = b * 256 + t;
    if (nd < N) off[nd] = beg + ex;
    if (nd == N - 1) off[N] = end;
    cur[t] = beg + ex;
    __syncthreads();
    for (int i = beg + t; i < end; i += 256) {
        int2 e = staged[i];
        int pos = atomicAdd(&cur[e.y & 255], 1);
        csr[pos] = e.x;
    }
}

// ---------------- Kernel E: softmax + aggregation, one wave per dst node ----------------
// No max pass (softmax shift-invariance; scores bounded, exp safe in fp32).
// Per 64-edge chunk: lanes compute (idx,w0,w1) -> LDS; channel loop consumes
// batches of 16 edges with 16 gathers in flight. Lane L holds channels {2L,2L+1}.
__global__ __launch_bounds__(256) void aggregate_kernel(
    const __hip_bfloat16* __restrict__ xp, const float2* __restrict__ asrc,
    const float2* __restrict__ adst, const int* __restrict__ off,
    const int* __restrict__ csr, const float* __restrict__ bias,
    const int* __restrict__ batch, float* __restrict__ out,
    float* __restrict__ gsum, int* __restrict__ gcnt, int N) {
    __shared__ float4 stage[4][64];
    int wid = threadIdx.x >> 6;
    int n = blockIdx.x * 4 + wid;
    if (n >= N) return;
    int lane = threadIdx.x & 63;
    float4* st = stage[wid];
    int o0 = off[n];
    int degE = off[n + 1] - o0;  // real edges only (self-loop analytic)
    float2 ad = adst[n];
    float2 asn = asrc[n];
    float es0 = asn.x + ad.x; es0 = (es0 > 0.f) ? es0 : NEG_SLOPE * es0;
    float es1 = asn.y + ad.y; es1 = (es1 > 0.f) ? es1 : NEG_SLOPE * es1;
    float ws0 = __expf(es0), ws1 = __expf(es1);
    // self-loop weight must enter the lane-reduced denominator exactly ONCE:
    float s0 = (lane == 0) ? ws0 : 0.f;
    float s1 = (lane == 0) ? ws1 : 0.f;

    const uint* xpw = reinterpret_cast<const uint*>(xp);
    float accx, accy;
    {   // self-loop contribution (per-lane channels -> not lane-reduced, full weight)
        float wgt = (lane < 32) ? ws0 : ws1;
        uint u = xpw[(size_t)n * 64 + lane];
        accx = wgt * __uint_as_float(u << 16);
        accy = wgt * __uint_as_float(u & 0xffff0000u);
    }

    for (int base = 0; base < degE; base += 64) {
        int i = base + lane;
        int idx = 0;
        float w0 = 0.f, w1 = 0.f;
        if (i < degE) {
            idx = csr[o0 + i];
            float2 as = asrc[idx];
            float t0 = as.x + ad.x; t0 = (t0 > 0.f) ? t0 : NEG_SLOPE * t0;
            float t1 = as.y + ad.y; t1 = (t1 > 0.f) ? t1 : NEG_SLOPE * t1;
            w0 = __expf(t0);
            w1 = __expf(t1);
        }
        s0 += w0;
        s1 += w1;
        st[lane] = make_float4(__int_as_float(idx), w0, w1, 0.f);
        int cnt = min(degE - base, 64);
        int nb16 = (cnt + 15) >> 4;  // padded slots carry w=0, idx=0 (harmless)
        for (int b = 0; b < nb16; b++) {
            float4 e[16];
#pragma unroll
            for (int j = 0; j < 16; j++) e[j] = st[b * 16 + j];
            uint bu[16];
#pragma unroll
            for (int j = 0; j < 16; j++) {
                int s2 = __float_as_int(e[j].x);
                bu[j] = xpw[(size_t)s2 * 64 + lane];
            }
#pragma unroll
            for (int j = 0; j < 16; j++) {
                float wgt = (lane < 32) ? e[j].y : e[j].z;
                accx = fmaf(wgt, __uint_as_float(bu[j] << 16), accx);
                accy = fmaf(wgt, __uint_as_float(bu[j] & 0xffff0000u), accy);
            }
        }
    }
#pragma unroll
    for (int d = 32; d > 0; d >>= 1) {
        s0 += __shfl_xor(s0, d, 64);
        s1 += __shfl_xor(s1, d, 64);
    }
    float inv = (lane < 32) ? (1.f / s0) : (1.f / s1);
    accx *= inv;
    accy *= inv;
    float ox = 0.5f * (accx + __shfl_xor(accx, 32, 64));
    float oy = 0.5f * (accy + __shfl_xor(accy, 32, 64));
    int g = batch[n];
    if (lane < 32) {
        float vx = ox + bias[2 * lane];
        float vy = oy + bias[2 * lane + 1];
        *reinterpret_cast<float2*>(out + (size_t)n * C + 2 * lane) = make_float2(vx, vy);
        atomicAdd(&gsum[(size_t)g * C + 2 * lane], vx);
        atomicAdd(&gsum[(size_t)g * C + 2 * lane + 1], vy);
    }
    if (lane == 0) atomicAdd(&gcnt[g], 1);
}

// ---------------- Kernel F: pool finalize ----------------
__global__ void pool_kernel(const float* __restrict__ gsum, const int* __restrict__ gcnt,
                            float* __restrict__ out, int G, int baseOff) {
    int i = blockIdx.x * blockDim.x + threadIdx.x;
    if (i >= G * C) return;
    int g = i >> 6;
    float cnt = (float)max(gcnt[g], 1);
    out[baseOff + i] = gsum[i] / cnt;
}

extern "C" void kernel_launch(void* const* d_in, const int* in_sizes, int n_in,
                              void* d_out, int out_size, void* d_ws, size_t ws_size,
                              hipStream_t stream) {
    const float* x       = (const float*)d_in[0];
    const int*   edge    = (const int*)d_in[1];
    const int*   batch   = (const int*)d_in[2];
    const float* W       = (const float*)d_in[3];
    const float* att_src = (const float*)d_in[4];
    const float* att_dst = (const float*)d_in[5];
    const float* bias    = (const float*)d_in[6];

    int N = in_sizes[0] / IN_CH;
    int E = in_sizes[1] / 2;
    int G = out_size / C - N;
    int nbuck = (N + 255) >> 8;            // 196 for N=50000 (must be <= 256)
    int chunkE = (E + NBLK - 1) / NBLK;

    char* p = (char*)d_ws;
    auto alloc = [&](size_t bytes) {
        char* r = p;
        p += (bytes + 255) & ~(size_t)255;
        return r;
    };
    __hip_bfloat16* xp = (__hip_bfloat16*)alloc((size_t)N * HC * 2);
    float* asrc    = (float*)alloc((size_t)N * H * 4);
    float* adst    = (float*)alloc((size_t)N * H * 4);
    int*   hist    = (int*)alloc((size_t)nbuck * NBLK * 4);
    int*   bucketBase = (int*)alloc((size_t)(nbuck + 1) * 4);
    int*   off     = (int*)alloc((size_t)(N + 1) * 4);
    int2*  staged  = (int2*)alloc((size_t)E * 8);
    int*   csr     = (int*)alloc((size_t)E * 4);
    float* gsum    = (float*)alloc((size_t)G * C * 4);
    int*   gcnt    = (int*)alloc((size_t)G * 4);

    hipMemsetAsync(gsum, 0, (size_t)G * C * 4, stream);
    hipMemsetAsync(gcnt, 0, (size_t)G * 4, stream);

    const int* srcE = edge;
    const int* dstE = edge + E;

    proj_kernel<<<2048, 128, 0, stream>>>(x, W, att_src, att_dst, xp, asrc, adst, N);
    hist_kernel<<<NBLK, 256, 0, stream>>>(dstE, hist, E, nbuck, chunkE);
    scan_hist_kernel<<<1, 1024, 0, stream>>>(hist, bucketBase, nbuck);
    bucket_scatter_kernel<<<NBLK, 256, 0, stream>>>(srcE, dstE, hist, staged, E, nbuck, chunkE);
    bucket_csr_kernel<<<nbuck, 256, 0, stream>>>(staged, bucketBase, off, csr, N);
    aggregate_kernel<<<(N + 3) / 4, 256, 0, stream>>>(xp, (const float2*)asrc, (const float2*)adst,
                                                      off, csr, bias, batch,
                                                      (float*)d_out, gsum, gcnt, N);
    pool_kernel<<<(G * C + 255) / 256, 256, 0, stream>>>(gsum, gcnt, (float*)d_out, G, N * C);
}